// Round 1
// baseline (530.291 us; speedup 1.0000x reference)
//
#include <hip/hip_runtime.h>
#include <math.h>

// Problem constants (fixed shapes from setup_inputs)
#define B 16
#define D 32
#define NH 8
#define NO 24            // D - NH
#define C 768
#define H 64
#define W 64
#define H1 512           // layer1 out
#define H2 256           // layer2 out
#define H3 117           // layer3 out
#define NP (NH * NO)     // 192 pairs per batch

// ---------------------------------------------------------------------------
// Kernel 1: ROI mean pooling.
// grid (B*D, 3), block 64. Each block = one box, one 256-channel chunk.
// Thread t handles float4 at channel chunk*256 + t*4. Memory-bound.
// ---------------------------------------------------------------------------
__global__ __launch_bounds__(64) void roi_pool_k(
    const float* __restrict__ feat, const float* __restrict__ boxes,
    float* __restrict__ pooled) {
  int bd = blockIdx.x;            // 0..511
  int b = bd >> 5;
  const float* bx = boxes + (size_t)bd * 4;
  float cx = bx[0], cy = bx[1], bw = bx[2], bh = bx[3];
  // Replicate reference rounding exactly: ((v)*896)/14, fp32 mul then div.
  int x1 = (int)floorf(__fdiv_rn(__fmul_rn(cx - 0.5f * bw, 896.0f), 14.0f));
  int y1 = (int)floorf(__fdiv_rn(__fmul_rn(cy - 0.5f * bh, 896.0f), 14.0f));
  int x2 = (int)floorf(__fdiv_rn(__fmul_rn(cx + 0.5f * bw, 896.0f), 14.0f));
  int y2 = (int)floorf(__fdiv_rn(__fmul_rn(cy + 0.5f * bh, 896.0f), 14.0f));
  // Mask semantics clip to the [0,64) grid.
  x1 = max(x1, 0); y1 = max(y1, 0); x2 = min(x2, W); y2 = min(y2, H);

  int c0 = blockIdx.y * 256 + threadIdx.x * 4;
  const float* fb = feat + (size_t)b * (H * W * C) + c0;
  float4 acc = make_float4(0.f, 0.f, 0.f, 0.f);
  for (int y = y1; y < y2; ++y) {
    const float* fr = fb + (size_t)y * (W * C);
    for (int x = x1; x < x2; ++x) {
      float4 v = *(const float4*)(fr + (size_t)x * C);
      acc.x += v.x; acc.y += v.y; acc.z += v.z; acc.w += v.w;
    }
  }
  float area = (float)((y2 - y1) * (x2 - x1));
  float4 r;
  r.x = __fdiv_rn(acc.x, area);
  r.y = __fdiv_rn(acc.y, area);
  r.z = __fdiv_rn(acc.z, area);
  r.w = __fdiv_rn(acc.w, area);
  *(float4*)(pooled + (size_t)bd * C + c0) = r;
}

// ---------------------------------------------------------------------------
// Kernel 2: stable descending argsort within the two groups (8 humans, 24 objs).
// grid (B), block 64 (32 active). Rank-sort: rank = #{greater} + #{equal, earlier}.
// ---------------------------------------------------------------------------
__global__ __launch_bounds__(64) void sort_k(
    const float* __restrict__ scores, int* __restrict__ hidx,
    int* __restrict__ oidx) {
  int b = blockIdx.x;
  int d = threadIdx.x;
  if (d >= D) return;
  const float* s = scores + (size_t)b * D;
  float v = s[d];
  if (d < NH) {
    int r = 0;
    for (int j = 0; j < NH; ++j) {
      float u = s[j];
      if (u > v || (u == v && j < d)) ++r;
    }
    hidx[b * NH + r] = d;
  } else {
    int r = 0;
    for (int j = NH; j < D; ++j) {
      float u = s[j];
      if (u > v || (u == v && j < d)) ++r;
    }
    oidx[b * NO + r] = d - NH;
  }
}

// ---------------------------------------------------------------------------
// Kernel 3: factored layer-1 GEMM.
// ph[b,d,:]  = pooled[b,d]      @ w1[0:768]            (humans, d<8, no bias)
// po[b,d-8,:]= pooled[b,d]      @ w1[768:1536] + b1    (objects)
// Rows in ORIGINAL order; the sort permutation is applied at pair-build time.
// grid (64 row-tiles of 8, 4 col-quarters of 128), block 128.
// Thread: 1 col, 8 row accumulators; rows staged in LDS, read as float4.
// ---------------------------------------------------------------------------
__global__ __launch_bounds__(128) void l1_k(
    const float* __restrict__ pooled, const float* __restrict__ w1,
    const float* __restrict__ b1, float* __restrict__ ph,
    float* __restrict__ po) {
  __shared__ float lds[8 * C];     // 24 KB
  int t = threadIdx.x;             // 0..127
  int tile = blockIdx.x;           // 0..63; tile&3==0 -> humans of batch tile>>2
  int rr0 = tile * 8;              // first global row (b*32+d)
  int b = rr0 >> 5;

  // Stage 8 contiguous pooled rows (6144 floats) into LDS.
  const float4* src = (const float4*)(pooled + (size_t)rr0 * C);
  float4* dst = (float4*)lds;
  #pragma unroll
  for (int i = 0; i < 12; ++i) dst[t + i * 128] = src[t + i * 128];
  __syncthreads();

  int col = blockIdx.y * 128 + t;  // 0..511
  bool human = ((tile & 3) == 0);
  int koff = human ? 0 : C;        // which half of w1
  const float* wc = w1 + (size_t)koff * H1 + col;

  float acc[8];
  #pragma unroll
  for (int r = 0; r < 8; ++r) acc[r] = 0.f;

  for (int k = 0; k < C; k += 4) {
    float w0 = wc[(size_t)(k + 0) * H1];
    float w1v = wc[(size_t)(k + 1) * H1];
    float w2v = wc[(size_t)(k + 2) * H1];
    float w3v = wc[(size_t)(k + 3) * H1];
    #pragma unroll
    for (int r = 0; r < 8; ++r) {
      float4 a = *(const float4*)(&lds[r * C + k]);
      acc[r] = fmaf(a.x, w0, acc[r]);
      acc[r] = fmaf(a.y, w1v, acc[r]);
      acc[r] = fmaf(a.z, w2v, acc[r]);
      acc[r] = fmaf(a.w, w3v, acc[r]);
    }
  }

  if (human) {
    #pragma unroll
    for (int r = 0; r < 8; ++r)
      ph[((size_t)b * NH + r) * H1 + col] = acc[r];
  } else {
    float bias = b1[col];          // bias folded into object half (added once)
    int dbase = (tile & 3) * 8 - NH;   // object index base (0,8,16)
    #pragma unroll
    for (int r = 0; r < 8; ++r)
      po[((size_t)b * NO + (dbase + r)) * H1 + col] = acc[r] + bias;
  }
}

// ---------------------------------------------------------------------------
// Kernel 4: pair build + layer-2 GEMM.
// x1 row(p=i*24+j) = relu(ph[b,hidx[i]] + po[b,oidx[j]])  (b1 already in po)
// x2 = relu(x1 @ w2 + b2)
// grid (B*24 row-tiles of 8 pairs, 2 col-halves of 128), block 128.
// ---------------------------------------------------------------------------
__global__ __launch_bounds__(128) void l2_k(
    const float* __restrict__ ph, const float* __restrict__ po,
    const int* __restrict__ hidx, const int* __restrict__ oidx,
    const float* __restrict__ w2, const float* __restrict__ b2,
    float* __restrict__ x2) {
  __shared__ float lds[8 * H1];    // 16 KB
  int t = threadIdx.x;             // 0..127
  int b = blockIdx.x / 24;
  int p0 = (blockIdx.x % 24) * 8;

  #pragma unroll
  for (int r = 0; r < 8; ++r) {
    int p = p0 + r;
    int i = p / NO;
    int j = p - i * NO;
    int hi = hidx[b * NH + i];
    int oj = oidx[b * NO + j];
    float4 a = *(const float4*)(ph + ((size_t)(b * NH + hi)) * H1 + t * 4);
    float4 c = *(const float4*)(po + ((size_t)(b * NO + oj)) * H1 + t * 4);
    float4 x;
    x.x = fmaxf(a.x + c.x, 0.f);
    x.y = fmaxf(a.y + c.y, 0.f);
    x.z = fmaxf(a.z + c.z, 0.f);
    x.w = fmaxf(a.w + c.w, 0.f);
    *(float4*)(&lds[r * H1 + t * 4]) = x;
  }
  __syncthreads();

  int col = blockIdx.y * 128 + t;  // 0..255
  const float* wc = w2 + col;
  float acc[8];
  #pragma unroll
  for (int r = 0; r < 8; ++r) acc[r] = 0.f;

  for (int k = 0; k < H1; k += 4) {
    float w0 = wc[(size_t)(k + 0) * H2];
    float w1v = wc[(size_t)(k + 1) * H2];
    float w2v = wc[(size_t)(k + 2) * H2];
    float w3v = wc[(size_t)(k + 3) * H2];
    #pragma unroll
    for (int r = 0; r < 8; ++r) {
      float4 a = *(const float4*)(&lds[r * H1 + k]);
      acc[r] = fmaf(a.x, w0, acc[r]);
      acc[r] = fmaf(a.y, w1v, acc[r]);
      acc[r] = fmaf(a.z, w2v, acc[r]);
      acc[r] = fmaf(a.w, w3v, acc[r]);
    }
  }

  float bias = b2[col];
  size_t g0 = (size_t)b * NP + p0;
  #pragma unroll
  for (int r = 0; r < 8; ++r)
    x2[(g0 + r) * H2 + col] = fmaxf(acc[r] + bias, 0.f);
}

// ---------------------------------------------------------------------------
// Kernel 5: layer-3 GEMM. out = x2 @ w3 + b3. grid (384 row-tiles), block 128
// (117 active compute lanes; all 128 help stage LDS).
// ---------------------------------------------------------------------------
__global__ __launch_bounds__(128) void l3_k(
    const float* __restrict__ x2, const float* __restrict__ w3,
    const float* __restrict__ b3, float* __restrict__ out) {
  __shared__ float lds[8 * H2];    // 8 KB
  int t = threadIdx.x;             // 0..127
  size_t g0 = (size_t)blockIdx.x * 8;

  #pragma unroll
  for (int r = 0; r < 8; ++r) {
    ((float2*)(&lds[r * H2]))[t] = ((const float2*)(x2 + (g0 + r) * H2))[t];
  }
  __syncthreads();

  if (t < H3) {
    int col = t;
    const float* wc = w3 + col;
    float acc[8];
    #pragma unroll
    for (int r = 0; r < 8; ++r) acc[r] = 0.f;
    for (int k = 0; k < H2; k += 4) {
      float w0 = wc[(size_t)(k + 0) * H3];
      float w1v = wc[(size_t)(k + 1) * H3];
      float w2v = wc[(size_t)(k + 2) * H3];
      float w3v = wc[(size_t)(k + 3) * H3];
      #pragma unroll
      for (int r = 0; r < 8; ++r) {
        float4 a = *(const float4*)(&lds[r * H2 + k]);
        acc[r] = fmaf(a.x, w0, acc[r]);
        acc[r] = fmaf(a.y, w1v, acc[r]);
        acc[r] = fmaf(a.z, w2v, acc[r]);
        acc[r] = fmaf(a.w, w3v, acc[r]);
      }
    }
    float bias = b3[col];
    #pragma unroll
    for (int r = 0; r < 8; ++r)
      out[(g0 + r) * H3 + col] = acc[r] + bias;
  }
}

// ---------------------------------------------------------------------------
extern "C" void kernel_launch(void* const* d_in, const int* in_sizes, int n_in,
                              void* d_out, int out_size, void* d_ws,
                              size_t ws_size, hipStream_t stream) {
  const float* feat   = (const float*)d_in[0];  // [16,64,64,768]
  const float* boxes  = (const float*)d_in[1];  // [16,32,4]
  const float* scores = (const float*)d_in[2];  // [16,32]
  const float* w1     = (const float*)d_in[3];  // [1536,512]
  const float* b1     = (const float*)d_in[4];  // [512]
  const float* w2     = (const float*)d_in[5];  // [512,256]
  const float* b2     = (const float*)d_in[6];  // [256]
  const float* w3     = (const float*)d_in[7];  // [256,117]
  const float* b3     = (const float*)d_in[8];  // [117]
  // d_in[9] labels: unused by the output.
  float* out = (float*)d_out;

  // Workspace layout (floats): ~5.8 MB total.
  float* pooled = (float*)d_ws;                 // 16*32*768   = 393216
  float* ph     = pooled + (size_t)B * D * C;   // 16*8*512    = 65536
  float* po     = ph + (size_t)B * NH * H1;     // 16*24*512   = 196608
  float* x2     = po + (size_t)B * NO * H1;     // 3072*256    = 786432
  int*   hidx   = (int*)(x2 + (size_t)B * NP * H2);  // 128
  int*   oidx   = hidx + B * NH;                     // 384

  roi_pool_k<<<dim3(B * D, 3), 64, 0, stream>>>(feat, boxes, pooled);
  sort_k<<<dim3(B), 64, 0, stream>>>(scores, hidx, oidx);
  l1_k<<<dim3(64, 4), 128, 0, stream>>>(pooled, w1, b1, ph, po);
  l2_k<<<dim3(B * 24, 2), 128, 0, stream>>>(ph, po, hidx, oidx, w2, b2, x2);
  l3_k<<<dim3(B * 24), 128, 0, stream>>>(x2, w3, b3, out);
}

// Round 2
// 385.285 us; speedup vs baseline: 1.3764x; 1.3764x over previous
//
#include <hip/hip_runtime.h>
#include <math.h>

#define B 16
#define D 32
#define NH 8
#define NO 24
#define C 768
#define H 64
#define W 64
#define H1 512
#define H2 256
#define H3 117
#define NP (NH * NO)     // 192

__device__ inline float4 f4add(float4 a, float4 b) {
  return make_float4(a.x + b.x, a.y + b.y, a.z + b.z, a.w + b.w);
}

// ---------------------------------------------------------------------------
// Kernel 1: ROI mean pooling. grid (512, 3), block 256 = 4 waves.
// Wave w handles rows y1+w, y1+w+4, ...; x-loop unrolled x4 with 4 independent
// accumulators to keep 4 loads in flight. LDS reduce across the 4 waves.
// ---------------------------------------------------------------------------
__global__ __launch_bounds__(256) void roi_pool_k(
    const float* __restrict__ feat, const float* __restrict__ boxes,
    float* __restrict__ pooled) {
  int bd = blockIdx.x;
  int b = bd >> 5;
  const float* bx = boxes + (size_t)bd * 4;
  float cx = bx[0], cy = bx[1], bw = bx[2], bh = bx[3];
  int xa = (int)floorf(__fdiv_rn(__fmul_rn(cx - 0.5f * bw, 896.0f), 14.0f));
  int ya = (int)floorf(__fdiv_rn(__fmul_rn(cy - 0.5f * bh, 896.0f), 14.0f));
  int xb = (int)floorf(__fdiv_rn(__fmul_rn(cx + 0.5f * bw, 896.0f), 14.0f));
  int yb = (int)floorf(__fdiv_rn(__fmul_rn(cy + 0.5f * bh, 896.0f), 14.0f));
  xa = max(xa, 0); ya = max(ya, 0); xb = min(xb, W); yb = min(yb, H);

  int t = threadIdx.x;
  int wv = t >> 6;          // wave 0..3 -> row group
  int lane = t & 63;
  int c0 = blockIdx.y * 256 + lane * 4;
  const float* fb = feat + (size_t)b * (H * W * C) + c0;

  float4 s0 = make_float4(0.f, 0.f, 0.f, 0.f);
  float4 s1 = s0, s2 = s0, s3 = s0;
  for (int y = ya + wv; y < yb; y += 4) {
    const float* fr = fb + (size_t)y * (W * C);
    int x = xa;
    for (; x + 3 < xb; x += 4) {
      float4 v0 = *(const float4*)(fr + (size_t)(x + 0) * C);
      float4 v1 = *(const float4*)(fr + (size_t)(x + 1) * C);
      float4 v2 = *(const float4*)(fr + (size_t)(x + 2) * C);
      float4 v3 = *(const float4*)(fr + (size_t)(x + 3) * C);
      s0 = f4add(s0, v0); s1 = f4add(s1, v1);
      s2 = f4add(s2, v2); s3 = f4add(s3, v3);
    }
    for (; x < xb; ++x)
      s0 = f4add(s0, *(const float4*)(fr + (size_t)x * C));
  }
  s0 = f4add(f4add(s0, s1), f4add(s2, s3));

  __shared__ float4 red[4][64];
  red[wv][lane] = s0;
  __syncthreads();
  if (wv == 0) {
    float4 a = f4add(f4add(red[0][lane], red[1][lane]),
                     f4add(red[2][lane], red[3][lane]));
    float area = (float)((yb - ya) * (xb - xa));
    float4 r;
    r.x = __fdiv_rn(a.x, area);
    r.y = __fdiv_rn(a.y, area);
    r.z = __fdiv_rn(a.z, area);
    r.w = __fdiv_rn(a.w, area);
    *(float4*)(pooled + (size_t)bd * C + c0) = r;
  }
}

// ---------------------------------------------------------------------------
// Kernel 2: stable descending rank-sort within groups (8 humans / 24 objects).
// ---------------------------------------------------------------------------
__global__ __launch_bounds__(64) void sort_k(
    const float* __restrict__ scores, int* __restrict__ hidx,
    int* __restrict__ oidx) {
  int b = blockIdx.x;
  int d = threadIdx.x;
  if (d >= D) return;
  const float* s = scores + (size_t)b * D;
  float v = s[d];
  if (d < NH) {
    int r = 0;
    for (int j = 0; j < NH; ++j) {
      float u = s[j];
      if (u > v || (u == v && j < d)) ++r;
    }
    hidx[b * NH + r] = d;
  } else {
    int r = 0;
    for (int j = NH; j < D; ++j) {
      float u = s[j];
      if (u > v || (u == v && j < d)) ++r;
    }
    oidx[b * NO + r] = d - NH;
  }
}

// ---------------------------------------------------------------------------
// Kernel 3: tiled transpose, in[R][Cc] -> out[Cc][R]. block (32,8).
// ---------------------------------------------------------------------------
__global__ __launch_bounds__(256) void transpose_k(
    const float* __restrict__ in, float* __restrict__ out, int R, int Cc) {
  __shared__ float tile[32][33];
  int c0 = blockIdx.x * 32, r0 = blockIdx.y * 32;
  int tx = threadIdx.x, ty = threadIdx.y;
  #pragma unroll
  for (int i = 0; i < 32; i += 8) {
    int r = r0 + ty + i, c = c0 + tx;
    if (r < R && c < Cc) tile[ty + i][tx] = in[(size_t)r * Cc + c];
  }
  __syncthreads();
  #pragma unroll
  for (int i = 0; i < 32; i += 8) {
    int c = c0 + ty + i, r = r0 + tx;
    if (c < Cc && r < R) out[(size_t)c * R + r] = tile[tx][ty + i];
  }
}

// ---------------------------------------------------------------------------
// Kernel 4: layer-1 GEMM, split-K x2. A (pooled rows) via wave-uniform scalar
// loads; W via k-contiguous dwordx4 from w1T with 1-chunk prefetch.
// grid (64 row-tiles, 2 col-halves, 2 k-halves), block 128; thread = 8r x 2c.
// No bias here (b1 added in pair_k).
// ---------------------------------------------------------------------------
__global__ __launch_bounds__(128) void l1_k(
    const float* __restrict__ pooled, const float* __restrict__ w1T,
    float* __restrict__ php, float* __restrict__ pop) {
  int t = threadIdx.x;
  int tile = blockIdx.x;      // 0..63
  int colh = blockIdx.y;      // 0..1
  int kh = blockIdx.z;        // 0..1
  int rr0 = tile * 8;
  int b = rr0 >> 5;
  bool human = ((tile & 3) == 0);
  int kbase = kh * 384;
  size_t wk = (size_t)(human ? 0 : C) + kbase;  // k-offset within w1T row (1536)
  int cA = colh * 256 + t;
  const float* wA = w1T + (size_t)cA * (2 * C) + wk;
  const float* wB = wA + (size_t)128 * (2 * C);
  const float* ap = pooled + (size_t)rr0 * C + kbase;

  float accA[8], accB[8];
  #pragma unroll
  for (int r = 0; r < 8; ++r) { accA[r] = 0.f; accB[r] = 0.f; }

  float4 wa = *(const float4*)wA;
  float4 wb = *(const float4*)wB;
  for (int k = 0; k < 384; k += 4) {
    // prefetch next chunk (last iter reads 16B past column end: stays in ws)
    float4 wa_n = *(const float4*)(wA + k + 4);
    float4 wb_n = *(const float4*)(wB + k + 4);
    #pragma unroll
    for (int r = 0; r < 8; ++r) {
      const float* ar = ap + (size_t)r * C + k;   // wave-uniform -> s_load
      float a0 = ar[0], a1 = ar[1], a2 = ar[2], a3 = ar[3];
      accA[r] = fmaf(a0, wa.x, accA[r]);
      accA[r] = fmaf(a1, wa.y, accA[r]);
      accA[r] = fmaf(a2, wa.z, accA[r]);
      accA[r] = fmaf(a3, wa.w, accA[r]);
      accB[r] = fmaf(a0, wb.x, accB[r]);
      accB[r] = fmaf(a1, wb.y, accB[r]);
      accB[r] = fmaf(a2, wb.z, accB[r]);
      accB[r] = fmaf(a3, wb.w, accB[r]);
    }
    wa = wa_n; wb = wb_n;
  }

  if (human) {
    #pragma unroll
    for (int r = 0; r < 8; ++r) {
      size_t row = (size_t)kh * (B * NH) + b * NH + r;
      php[row * H1 + cA] = accA[r];
      php[row * H1 + cA + 128] = accB[r];
    }
  } else {
    int dbase = (tile & 3) * 8 - NH;
    #pragma unroll
    for (int r = 0; r < 8; ++r) {
      size_t row = (size_t)kh * (B * NO) + b * NO + dbase + r;
      pop[row * H1 + cA] = accA[r];
      pop[row * H1 + cA + 128] = accB[r];
    }
  }
}

// ---------------------------------------------------------------------------
// Kernel 5: pair build. x1[b,p,:] = relu(ph[hi] + po[oj] + b1), summing the
// two K-halves. grid (3072), block 128 (one pair-row, 512 floats as float4).
// ---------------------------------------------------------------------------
__global__ __launch_bounds__(128) void pair_k(
    const float* __restrict__ php, const float* __restrict__ pop,
    const float* __restrict__ b1, const int* __restrict__ hidx,
    const int* __restrict__ oidx, float* __restrict__ x1) {
  int row = blockIdx.x;
  int b = row / NP;
  int p = row % NP;
  int i = p / NO, j = p % NO;
  int hi = hidx[b * NH + i];
  int oj = oidx[b * NO + j];
  int t = threadIdx.x;
  const float4* h0 = (const float4*)(php + ((size_t)(b * NH + hi)) * H1);
  const float4* h1 = (const float4*)(php + ((size_t)(B * NH + b * NH + hi)) * H1);
  const float4* o0 = (const float4*)(pop + ((size_t)(b * NO + oj)) * H1);
  const float4* o1 = (const float4*)(pop + ((size_t)(B * NO + b * NO + oj)) * H1);
  const float4* bb = (const float4*)b1;
  float4 v = f4add(f4add(h0[t], h1[t]), f4add(o0[t], o1[t]));
  v = f4add(v, bb[t]);
  v.x = fmaxf(v.x, 0.f); v.y = fmaxf(v.y, 0.f);
  v.z = fmaxf(v.z, 0.f); v.w = fmaxf(v.w, 0.f);
  ((float4*)(x1 + (size_t)row * H1))[t] = v;
}

// ---------------------------------------------------------------------------
// Kernel 6: layer-2 GEMM. x2 = relu(x1 @ w2 + b2). grid (384), block 128;
// thread = 8 rows x 2 cols (t, t+128). A scalar-loaded, W from w2T.
// ---------------------------------------------------------------------------
__global__ __launch_bounds__(128) void l2_k(
    const float* __restrict__ x1, const float* __restrict__ w2T,
    const float* __restrict__ b2, float* __restrict__ x2) {
  int t = threadIdx.x;
  size_t r0 = (size_t)blockIdx.x * 8;
  const float* wA = w2T + (size_t)t * H1;
  const float* wB = w2T + (size_t)(t + 128) * H1;
  const float* ap = x1 + r0 * H1;

  float accA[8], accB[8];
  #pragma unroll
  for (int r = 0; r < 8; ++r) { accA[r] = 0.f; accB[r] = 0.f; }

  float4 wa = *(const float4*)wA;
  float4 wb = *(const float4*)wB;
  for (int k = 0; k < H1; k += 4) {
    float4 wa_n = *(const float4*)(wA + k + 4);
    float4 wb_n = *(const float4*)(wB + k + 4);
    #pragma unroll
    for (int r = 0; r < 8; ++r) {
      const float* ar = ap + (size_t)r * H1 + k;
      float a0 = ar[0], a1 = ar[1], a2 = ar[2], a3 = ar[3];
      accA[r] = fmaf(a0, wa.x, accA[r]);
      accA[r] = fmaf(a1, wa.y, accA[r]);
      accA[r] = fmaf(a2, wa.z, accA[r]);
      accA[r] = fmaf(a3, wa.w, accA[r]);
      accB[r] = fmaf(a0, wb.x, accB[r]);
      accB[r] = fmaf(a1, wb.y, accB[r]);
      accB[r] = fmaf(a2, wb.z, accB[r]);
      accB[r] = fmaf(a3, wb.w, accB[r]);
    }
    wa = wa_n; wb = wb_n;
  }

  float bA = b2[t], bB = b2[t + 128];
  #pragma unroll
  for (int r = 0; r < 8; ++r) {
    x2[(r0 + r) * H2 + t] = fmaxf(accA[r] + bA, 0.f);
    x2[(r0 + r) * H2 + t + 128] = fmaxf(accB[r] + bB, 0.f);
  }
}

// ---------------------------------------------------------------------------
// Kernel 7: layer-3 GEMM. out = x2 @ w3 + b3. grid (384), block 128
// (117 active); thread = 8 rows x 1 col.
// ---------------------------------------------------------------------------
__global__ __launch_bounds__(128) void l3_k(
    const float* __restrict__ x2, const float* __restrict__ w3T,
    const float* __restrict__ b3, float* __restrict__ out) {
  int t = threadIdx.x;
  if (t >= H3) return;
  size_t r0 = (size_t)blockIdx.x * 8;
  const float* wc = w3T + (size_t)t * H2;
  const float* ap = x2 + r0 * H2;

  float acc[8];
  #pragma unroll
  for (int r = 0; r < 8; ++r) acc[r] = 0.f;

  float4 wa = *(const float4*)wc;
  for (int k = 0; k < H2; k += 4) {
    float4 wa_n = *(const float4*)(wc + k + 4);
    #pragma unroll
    for (int r = 0; r < 8; ++r) {
      const float* ar = ap + (size_t)r * H2 + k;
      acc[r] = fmaf(ar[0], wa.x, acc[r]);
      acc[r] = fmaf(ar[1], wa.y, acc[r]);
      acc[r] = fmaf(ar[2], wa.z, acc[r]);
      acc[r] = fmaf(ar[3], wa.w, acc[r]);
    }
    wa = wa_n;
  }
  float bias = b3[t];
  #pragma unroll
  for (int r = 0; r < 8; ++r)
    out[(r0 + r) * H3 + t] = acc[r] + bias;
}

// ---------------------------------------------------------------------------
extern "C" void kernel_launch(void* const* d_in, const int* in_sizes, int n_in,
                              void* d_out, int out_size, void* d_ws,
                              size_t ws_size, hipStream_t stream) {
  const float* feat   = (const float*)d_in[0];
  const float* boxes  = (const float*)d_in[1];
  const float* scores = (const float*)d_in[2];
  const float* w1     = (const float*)d_in[3];  // [1536,512]
  const float* b1     = (const float*)d_in[4];
  const float* w2     = (const float*)d_in[5];  // [512,256]
  const float* b2     = (const float*)d_in[6];
  const float* w3     = (const float*)d_in[7];  // [256,117]
  const float* b3     = (const float*)d_in[8];
  float* out = (float*)d_out;

  // Workspace layout (floats). x2 aliases pooled+w1T (both dead after l1).
  float* base   = (float*)d_ws;
  float* pooled = base;                            // 393216
  float* w1T    = base + 393216;                   // 786432  [512][1536]
  float* x2     = base;                            // 786432 (alias)
  float* w2T    = base + 1179648;                  // 131072  [256][512]
  float* w3T    = base + 1310720;                  // 29952   [117][256]
  float* php    = base + 1340672;                  // 2*16*8*512  = 131072
  float* pop    = base + 1471744;                  // 2*16*24*512 = 393216
  float* x1     = base + 1864960;                  // 3072*512 = 1572864
  int*   hidx   = (int*)(base + 3437824);          // 128
  int*   oidx   = hidx + B * NH;                   // 384
  // total ~13.8 MB

  roi_pool_k<<<dim3(B * D, 3), 256, 0, stream>>>(feat, boxes, pooled);
  sort_k<<<dim3(B), 64, 0, stream>>>(scores, hidx, oidx);
  transpose_k<<<dim3(16, 48), dim3(32, 8), 0, stream>>>(w1, w1T, 2 * C, H1);
  transpose_k<<<dim3(8, 16), dim3(32, 8), 0, stream>>>(w2, w2T, H1, H2);
  transpose_k<<<dim3(4, 8), dim3(32, 8), 0, stream>>>(w3, w3T, H2, H3);
  l1_k<<<dim3(64, 2, 2), 128, 0, stream>>>(pooled, w1T, php, pop);
  pair_k<<<dim3(B * NP), 128, 0, stream>>>(php, pop, b1, hidx, oidx, x1);
  l2_k<<<dim3(B * NP / 8), 128, 0, stream>>>(x1, w2T, b2, x2);
  l3_k<<<dim3(B * NP / 8), 128, 0, stream>>>(x2, w3T, b3, out);
}